// Round 11
// baseline (501.538 us; speedup 1.0000x reference)
//
#include <hip/hip_runtime.h>

#define H 64
#define BNODE_SHIFT 8           // 256 nodes per bucket
#define BNODES 256
#define CHUNK 4096              // edges per sort block (16 per thread)
#define EPT 16

// bf16 helpers: bf16->fp32 is exact (bit shift); fp32->bf16 round-to-nearest-even
static __device__ __forceinline__ float b2f(ushort b) {
    return __uint_as_float(((unsigned int)b) << 16);
}
static __device__ __forceinline__ ushort f2b(float f) {
    unsigned int u = __float_as_uint(f);
    return (ushort)((u + 0x7FFF + ((u >> 16) & 1)) >> 16);
}
#define RFL(x) __builtin_amdgcn_readfirstlane(x)

// ---------------- zero-fill ----------------
__global__ void zero_i32(int* p, int n) {
    int i = blockIdx.x * blockDim.x + threadIdx.x;
    if (i < n) p[i] = 0;
}
__global__ void zero_f32(float* p, int n) {
    int i = blockIdx.x * blockDim.x + threadIdx.x;
    if (i < n) p[i] = 0.f;
}

// ---------------- bucket histogram (LDS-local then merge) ----------------
__global__ void bucket_hist(const int* __restrict__ dst, int E,
                            int* __restrict__ bcounts, int nbuck) {
    __shared__ int hist[512];
    for (int i = threadIdx.x; i < nbuck; i += blockDim.x) hist[i] = 0;
    __syncthreads();
    for (int e = blockIdx.x * blockDim.x + threadIdx.x; e < E; e += gridDim.x * blockDim.x)
        atomicAdd(&hist[dst[e] >> BNODE_SHIFT], 1);
    __syncthreads();
    for (int i = threadIdx.x; i < nbuck; i += blockDim.x) {
        int v = hist[i];
        if (v) atomicAdd(&bcounts[i], v);
    }
}

// ---------------- bucket offsets scan (1 block) ----------------
__global__ void bucket_scan(const int* __restrict__ bcounts, int* __restrict__ boff,
                            int* __restrict__ bcur, int* __restrict__ rowstart,
                            int nbuck, int E, int N) {
    __shared__ int t[1024];
    int tid = threadIdx.x;
    int v = (tid < nbuck) ? bcounts[tid] : 0;
    t[tid] = v;
    __syncthreads();
    for (int off = 1; off < 1024; off <<= 1) {
        int x = (tid >= off) ? t[tid - off] : 0;
        __syncthreads();
        t[tid] += x;
        __syncthreads();
    }
    if (tid < nbuck) {
        int o = t[tid] - v;       // exclusive
        boff[tid] = o;
        bcur[tid * 16] = o;       // 64B-padded cursor
    }
    if (tid == 0) { boff[nbuck] = E; rowstart[N] = E; }
}

// ---------------- block-local LDS sort + fully parallel flush ----------------
// pack: src (bits 0..19) | local_dst (bits 20..27)
__global__ void edge_sort_scatter(const int* __restrict__ src, const int* __restrict__ dst,
                                  int E, int nbuck,
                                  int* __restrict__ bcur, int* __restrict__ pairs4) {
    __shared__ int hist[392];
    __shared__ int bstart[393];
    __shared__ int cur[392];
    __shared__ int gbase[392];
    __shared__ int wsum[256];
    __shared__ int packed[CHUNK];   // 16 KB
    __shared__ int gpos[CHUNK];     // 16 KB

    int t = threadIdx.x;
    int chunkBase = blockIdx.x * CHUNK;

    // phase 1: local histogram
    for (int i = t; i < nbuck; i += 256) hist[i] = 0;
    __syncthreads();
#pragma unroll
    for (int k = 0; k < EPT; ++k) {
        int e = chunkBase + t + k * 256;
        if (e < E) atomicAdd(&hist[dst[e] >> BNODE_SHIFT], 1);
    }
    __syncthreads();

    // phase 2: exclusive scan of hist (2 items/thread covers <=512 buckets)
    int a0 = (2 * t < nbuck) ? hist[2 * t] : 0;
    int a1 = (2 * t + 1 < nbuck) ? hist[2 * t + 1] : 0;
    int s2 = a0 + a1;
    wsum[t] = s2;
    __syncthreads();
    for (int off = 1; off < 256; off <<= 1) {
        int x = (t >= off) ? wsum[t - off] : 0;
        __syncthreads();
        wsum[t] += x;
        __syncthreads();
    }
    int base = wsum[t] - s2;        // exclusive
    if (2 * t < nbuck)     bstart[2 * t] = base;
    if (2 * t + 1 < nbuck) bstart[2 * t + 1] = base + a0;
    if (t == 255) bstart[nbuck] = wsum[255];
    __syncthreads();

    // phase 2b: reserve global spans; init local cursors
    for (int b = t; b < nbuck; b += 256) {
        int cnt = bstart[b + 1] - bstart[b];
        gbase[b] = cnt ? (atomicAdd(&bcur[b * 16], cnt) - bstart[b]) : 0;
        cur[b] = bstart[b];
    }
    __syncthreads();

    // phase 3: place edges sorted into LDS; record final global position
    #pragma unroll
    for (int k = 0; k < EPT; ++k) {
        int e = chunkBase + t + k * 256;
        if (e < E) {
            int d = dst[e];
            int b = d >> BNODE_SHIFT;
            int pos = atomicAdd(&cur[b], 1);
            packed[pos] = src[e] | ((d & (BNODES - 1)) << 20);
            gpos[pos] = gbase[b] + pos;   // gbase pre-biased by -bstart[b]
        }
    }
    __syncthreads();

    // phase 4: flat parallel flush (coalesced LDS read; runs are contiguous globally)
    int nloc = bstart[nbuck];
    for (int j = t; j < nloc; j += 256)
        pairs4[gpos[j]] = packed[j];
}

// ---------------- exact CSR within each bucket (LDS atomics) ----------------
__global__ void bucket_build(const int* __restrict__ pairs4, const int* __restrict__ boff,
                             int* __restrict__ col, int* __restrict__ rowstart,
                             float* __restrict__ dinv, int N) {
    __shared__ int hist[BNODES];
    __shared__ int cur[BNODES];
    int b = blockIdx.x;
    int lo = boff[b], hi = boff[b + 1];
    int node0 = b << BNODE_SHIFT;
    int tid = threadIdx.x;
    hist[tid] = 0;
    __syncthreads();
    for (int e = lo + tid; e < hi; e += 256)
        atomicAdd(&hist[(pairs4[e] >> 20) & (BNODES - 1)], 1);
    __syncthreads();
    int v = hist[tid];
    cur[tid] = v;
    __syncthreads();
    for (int off = 1; off < BNODES; off <<= 1) {
        int x = (tid >= off) ? cur[tid - off] : 0;
        __syncthreads();
        cur[tid] += x;
        __syncthreads();
    }
    {
        int ex = cur[tid] - v;    // exclusive
        int node = node0 + tid;
        if (node < N) {
            rowstart[node] = lo + ex;
            dinv[node] = rsqrtf((float)(v + 1));   // +1 self-loop
        }
        cur[tid] = ex;            // local cursor
    }
    __syncthreads();
    for (int e = lo + tid; e < hi; e += 256) {
        int pr = pairs4[e];
        int p = atomicAdd(&cur[(pr >> 20) & (BNODES - 1)], 1);
        col[lo + p] = pr & 0xFFFFF;
    }
}

// ---------------- graph boundaries from sorted batch (no atomics) ----------------
__global__ void graph_bounds(const int* __restrict__ batch, int* __restrict__ nodestart,
                             int N, int G) {
    int i = blockIdx.x * blockDim.x + threadIdx.x;
    if (i >= N) return;
    int b = batch[i];
    int bp = (i == 0) ? -1 : batch[i - 1];
    for (int g = bp + 1; g <= b; ++g) nodestart[g] = i;
    if (i == N - 1) nodestart[G] = N;
}

// ---------------- prep: pad x to 16 bf16/row (32B), pre-scaled by dinv ----------------
__global__ void prep_xb(const float* __restrict__ x, const float* __restrict__ dinv,
                        ushort* __restrict__ xb, int N) {
    int i = blockIdx.x * blockDim.x + threadIdx.x;
    if (i >= N * 16) return;
    int n = i >> 4, k = i & 15;
    xb[i] = (k < 9) ? f2b(x[n * 9 + k] * dinv[n]) : (ushort)0;
}

// ---------------- conv1 fused: agg = dinv_i*(sum xb[src] + xb[i]); hb = dinv_i*relu(agg@W1+b1)
__global__ void conv1_fused(const ushort* __restrict__ xb, const float* __restrict__ dinv,
                            const int* __restrict__ rowstart,
                            const int* __restrict__ col, const float* __restrict__ W1,
                            const float* __restrict__ b1, ushort* __restrict__ outb, int N) {
    int gtid = blockIdx.x * blockDim.x + threadIdx.x;
    int i = RFL(gtid >> 6);
    int lane = threadIdx.x & 63;
    int f16 = lane & 15, grp = lane >> 4;
    if (i >= N) return;
    float di = dinv[i];
    float sv = b2f(xb[(size_t)i * 16 + f16]);   // self (already dinv_i-scaled)
    float acc = 0.f;
    int s = rowstart[i], e = rowstart[i + 1];
    for (int base = s; base < e; base += 64) {
        int cnt = e - base;
        if (cnt > 64) cnt = 64;
        int idx = 0;
        if (lane < cnt) idx = col[base + lane];
        for (int j = 0; j < cnt; j += 8) {
            int j0 = j + grp, j1 = j + 4 + grp;
            int s0 = __shfl(idx, j0);
            int s1 = __shfl(idx, j1 & 63);
            float v0 = (j0 < cnt) ? b2f(xb[(size_t)s0 * 16 + f16]) : 0.f;
            float v1 = (j1 < cnt) ? b2f(xb[(size_t)s1 * 16 + f16]) : 0.f;
            acc += v0 + v1;
        }
    }
    // reduce 4 edge-groups
    acc += __shfl_xor(acc, 16);
    acc += __shfl_xor(acc, 32);
    float aggf = di * (acc + sv);            // lane k (k<9) holds agg[k]

    float o = b1[lane];
#pragma unroll
    for (int k = 0; k < 9; ++k) {
        float ak = __shfl(aggf, k);
        o = fmaf(ak, W1[k * H + lane], o);
    }
    outb[(size_t)i * H + lane] = f2b(fmaxf(o, 0.f) * di);
}

// ---------------- fused aggregate + 64x64 matvec ----------------
// hb pre-scaled by dinv[src]; agg = dinv_i*(sum hb[src] + hb[i]); o = relu(b + agg@W)
// MODE 0: write bf16 dinv_i*o (next conv's operand). MODE 1: atomic pool accumulate.
template <int MODE>
__global__ void agg_mm(const ushort* __restrict__ hb, const float* __restrict__ dinv,
                       const int* __restrict__ rowstart, const int* __restrict__ col,
                       const float* __restrict__ W, const float* __restrict__ bias,
                       ushort* __restrict__ outb, float* __restrict__ pool,
                       const int* __restrict__ batch, int N) {
    __shared__ float Ws[H * H];   // 16 KB
    int t = threadIdx.x;
    for (int idx = t; idx < H * H; idx += 256) Ws[idx] = W[idx];

    int gtid = blockIdx.x * blockDim.x + t;
    int i = RFL(gtid >> 6);      // node = wave (uniform, SGPR)
    int f = t & 63;
    bool active = (i < N);
    float acc = 0.f, di = 0.f;
    int s = 0, e = 0;
    if (active) {
        di = dinv[i];
        acc = b2f(hb[(size_t)i * H + f]);   // self-loop term
        s = rowstart[i];
        e = rowstart[i + 1];
    }
    int p = s;
    for (; p + 8 <= e; p += 8) {
        int i0 = RFL(col[p + 0]);
        int i1 = RFL(col[p + 1]);
        int i2 = RFL(col[p + 2]);
        int i3 = RFL(col[p + 3]);
        int i4 = RFL(col[p + 4]);
        int i5 = RFL(col[p + 5]);
        int i6 = RFL(col[p + 6]);
        int i7 = RFL(col[p + 7]);
        float v0 = b2f(hb[(size_t)i0 * H + f]);
        float v1 = b2f(hb[(size_t)i1 * H + f]);
        float v2 = b2f(hb[(size_t)i2 * H + f]);
        float v3 = b2f(hb[(size_t)i3 * H + f]);
        float v4 = b2f(hb[(size_t)i4 * H + f]);
        float v5 = b2f(hb[(size_t)i5 * H + f]);
        float v6 = b2f(hb[(size_t)i6 * H + f]);
        float v7 = b2f(hb[(size_t)i7 * H + f]);
        acc += ((v0 + v1) + (v2 + v3)) + ((v4 + v5) + (v6 + v7));
    }
    for (; p < e; ++p) {
        int s0 = RFL(col[p]);
        acc += b2f(hb[(size_t)s0 * H + f]);
    }
    __syncthreads();             // Ws ready (all threads reach: no early return)
    if (!active) return;

    float aggv = di * acc;       // lane k holds agg[k]
    float o = bias[f];
#pragma unroll
    for (int k = 0; k < H; ++k) {
        float ak = __shfl(aggv, k);
        o = fmaf(ak, Ws[k * H + f], o);
    }
    o = fmaxf(o, 0.f);
    if (MODE == 0) {
        outb[(size_t)i * H + f] = f2b(o * di);
    } else {
        atomicAdd(&pool[(size_t)batch[i] * H + f], o);
    }
}

// ---------------- final MLP: one wave per graph, shfl-based ----------------
__global__ void mlp(const float* __restrict__ pool, const int* __restrict__ nodestart,
                    const float* __restrict__ u,
                    const float* __restrict__ A1, const float* __restrict__ c1,
                    const float* __restrict__ A2, const float* __restrict__ c2,
                    const float* __restrict__ A3, const float* __restrict__ c3,
                    const float* __restrict__ A4, const float* __restrict__ c4,
                    const float* __restrict__ A5, const float* __restrict__ c5,
                    float* __restrict__ out, int G) {
    int wid = (blockIdx.x * blockDim.x + threadIdx.x) >> 6;  // wave = graph
    int lane = threadIdx.x & 63;
    if (wid >= G) return;
    int g = wid;

    float cntf = (float)(nodestart[g + 1] - nodestart[g]);
    float inv = 1.f / fmaxf(cntf, 1.f);
    float zreg = pool[g * H + lane] * inv;
    float u0 = u[g * 4 + 0], u1 = u[g * 4 + 1], u2 = u[g * 4 + 2], u3 = u[g * 4 + 3];

    // layer 1: 68 -> 50
    float acc = (lane < 50) ? c1[lane] : 0.f;
#pragma unroll
    for (int k = 0; k < 64; ++k) {
        float zk = __shfl(zreg, k);
        float w = (lane < 50) ? A1[k * 50 + lane] : 0.f;
        acc = fmaf(zk, w, acc);
    }
    {
        float w;
        w = (lane < 50) ? A1[64 * 50 + lane] : 0.f; acc = fmaf(u0, w, acc);
        w = (lane < 50) ? A1[65 * 50 + lane] : 0.f; acc = fmaf(u1, w, acc);
        w = (lane < 50) ? A1[66 * 50 + lane] : 0.f; acc = fmaf(u2, w, acc);
        w = (lane < 50) ? A1[67 * 50 + lane] : 0.f; acc = fmaf(u3, w, acc);
    }
    float z1v = fmaxf(acc, 0.f);

    // layer 2: 50 -> 30
    acc = (lane < 30) ? c2[lane] : 0.f;
#pragma unroll
    for (int k = 0; k < 50; ++k) {
        float zk = __shfl(z1v, k);
        float w = (lane < 30) ? A2[k * 30 + lane] : 0.f;
        acc = fmaf(zk, w, acc);
    }
    float z2v = fmaxf(acc, 0.f);

    // layer 3: 30 -> 20
    acc = (lane < 20) ? c3[lane] : 0.f;
#pragma unroll
    for (int k = 0; k < 30; ++k) {
        float zk = __shfl(z2v, k);
        float w = (lane < 20) ? A3[k * 20 + lane] : 0.f;
        acc = fmaf(zk, w, acc);
    }
    float z3v = fmaxf(acc, 0.f);

    // layer 4: 20 -> 5
    acc = (lane < 5) ? c4[lane] : 0.f;
#pragma unroll
    for (int k = 0; k < 20; ++k) {
        float zk = __shfl(z3v, k);
        float w = (lane < 5) ? A4[k * 5 + lane] : 0.f;
        acc = fmaf(zk, w, acc);
    }
    float z4v = fmaxf(acc, 0.f);

    // layer 5: 5 -> 1
    acc = c5[0];
#pragma unroll
    for (int k = 0; k < 5; ++k) {
        float zk = __shfl(z4v, k);
        acc = fmaf(zk, A5[k], acc);
    }
    if (lane == 0) out[g] = fmaxf(acc, 0.f);
}

extern "C" void kernel_launch(void* const* d_in, const int* in_sizes, int n_in,
                              void* d_out, int out_size, void* d_ws, size_t ws_size,
                              hipStream_t stream) {
    const float* x     = (const float*)d_in[0];
    const int*   edge  = (const int*)d_in[1];
    const int*   batch = (const int*)d_in[2];
    const float* u     = (const float*)d_in[3];
    const float* W1 = (const float*)d_in[4];  const float* b1 = (const float*)d_in[5];
    const float* W2 = (const float*)d_in[6];  const float* b2 = (const float*)d_in[7];
    const float* W3 = (const float*)d_in[8];  const float* b3 = (const float*)d_in[9];
    const float* A1 = (const float*)d_in[10]; const float* c1 = (const float*)d_in[11];
    const float* A2 = (const float*)d_in[12]; const float* c2 = (const float*)d_in[13];
    const float* A3 = (const float*)d_in[14]; const float* c3 = (const float*)d_in[15];
    const float* A4 = (const float*)d_in[16]; const float* c4 = (const float*)d_in[17];
    const float* A5 = (const float*)d_in[18]; const float* c5 = (const float*)d_in[19];

    const int N = in_sizes[2];          // 100000
    const int E = in_sizes[1] / 2;      // 3200000
    const int G = in_sizes[3] / 4;      // 256
    const int* src = edge;
    const int* dst = edge + E;
    const int nbuck = (N + BNODES - 1) >> BNODE_SHIFT;   // 391

    // ---- workspace layout (pairs4 aliases hb_a: pairs4 dead before conv1 writes) ----
    char* ws = (char*)d_ws;
    size_t off = 0;
    auto alloc = [&](size_t bytes) -> void* {
        void* p = ws + off;
        off = (off + bytes + 255) & ~(size_t)255;
        return p;
    };
    ushort* hb_a     = (ushort*)alloc((size_t)N * H * 2);  // bf16 operand A; aliases pairs4
    ushort* hb_b     = (ushort*)alloc((size_t)N * H * 2);  // bf16 operand B
    int*    col      = (int*)alloc((size_t)E * 4);
    ushort* xb       = (ushort*)alloc((size_t)N * 16 * 2);
    int*    rowstart = (int*)alloc((size_t)(N + 1) * 4);
    float*  dinv     = (float*)alloc((size_t)N * 4);
    int*    bcounts  = (int*)alloc((size_t)nbuck * 4);
    int*    boff     = (int*)alloc((size_t)(nbuck + 1) * 4);
    int*    bcur     = (int*)alloc((size_t)nbuck * 64);    // 64B-padded cursors
    int*    nodestart= (int*)alloc((size_t)(G + 1) * 4);
    float*  pool     = (float*)alloc((size_t)G * H * 4);
    int*    pairs4   = (int*)hb_a;    // E*4 = 12.8MB == N*H*2

    const int nbN   = (N + 255) / 256;
    const int nbAgg = (N + 3) / 4;       // 4 waves/block, wave per node
    const int nchunks = (E + CHUNK - 1) / CHUNK;   // 782

    // ---- CSR build via block-local LDS sort ----
    zero_i32<<<(nbuck + 255) / 256, 256, 0, stream>>>(bcounts, nbuck);
    zero_f32<<<(G * H + 255) / 256, 256, 0, stream>>>(pool, G * H);
    bucket_hist<<<256, 256, 0, stream>>>(dst, E, bcounts, nbuck);
    bucket_scan<<<1, 1024, 0, stream>>>(bcounts, boff, bcur, rowstart, nbuck, E, N);
    edge_sort_scatter<<<nchunks, 256, 0, stream>>>(src, dst, E, nbuck, bcur, pairs4);
    bucket_build<<<nbuck, 256, 0, stream>>>(pairs4, boff, col, rowstart, dinv, N);
    graph_bounds<<<nbN, 256, 0, stream>>>(batch, nodestart, N, G);

    // ---- conv1 (fused: aggregate 9-wide raw bf16 x, then W1; bf16 out) ----
    prep_xb<<<(N * 16 + 255) / 256, 256, 0, stream>>>(x, dinv, xb, N);
    conv1_fused<<<nbAgg, 256, 0, stream>>>(xb, dinv, rowstart, col, W1, b1, hb_a, N);
    // ---- conv2 (fused aggregate + matvec) ----
    agg_mm<0><<<nbAgg, 256, 0, stream>>>(hb_a, dinv, rowstart, col, W2, b2,
                                         hb_b, nullptr, nullptr, N);
    // ---- conv3 (fused aggregate + matvec + pooling) ----
    agg_mm<1><<<nbAgg, 256, 0, stream>>>(hb_b, dinv, rowstart, col, W3, b3,
                                         nullptr, pool, batch, N);

    // ---- final MLP over 256 graphs ----
    mlp<<<(G * 64 + 255) / 256, 256, 0, stream>>>(pool, nodestart, u, A1, c1, A2, c2,
                                                  A3, c3, A4, c4, A5, c5,
                                                  (float*)d_out, G);
}

// Round 12
// 422.420 us; speedup vs baseline: 1.1873x; 1.1873x over previous
//
#include <hip/hip_runtime.h>

#define H 64
#define BNODE_SHIFT 8           // 256 nodes per bucket
#define BNODES 256
#define CHUNK 4096              // edges per sort block (16 per thread)
#define EPT 16

// bf16 helpers: bf16->fp32 is exact (bit shift); fp32->bf16 round-to-nearest-even
static __device__ __forceinline__ float b2f(ushort b) {
    return __uint_as_float(((unsigned int)b) << 16);
}
static __device__ __forceinline__ ushort f2b(float f) {
    unsigned int u = __float_as_uint(f);
    return (ushort)((u + 0x7FFF + ((u >> 16) & 1)) >> 16);
}
#define RFL(x) __builtin_amdgcn_readfirstlane(x)

// ---------------- zero-fill ----------------
__global__ void zero_i32(int* p, int n) {
    int i = blockIdx.x * blockDim.x + threadIdx.x;
    if (i < n) p[i] = 0;
}

// ---------------- bucket histogram (LDS-local then merge) ----------------
__global__ void bucket_hist(const int* __restrict__ dst, int E,
                            int* __restrict__ bcounts, int nbuck) {
    __shared__ int hist[512];
    for (int i = threadIdx.x; i < nbuck; i += blockDim.x) hist[i] = 0;
    __syncthreads();
    for (int e = blockIdx.x * blockDim.x + threadIdx.x; e < E; e += gridDim.x * blockDim.x)
        atomicAdd(&hist[dst[e] >> BNODE_SHIFT], 1);
    __syncthreads();
    for (int i = threadIdx.x; i < nbuck; i += blockDim.x) {
        int v = hist[i];
        if (v) atomicAdd(&bcounts[i], v);
    }
}

// ---------------- bucket offsets scan (1 block) ----------------
__global__ void bucket_scan(const int* __restrict__ bcounts, int* __restrict__ boff,
                            int* __restrict__ bcur, int* __restrict__ rowstart,
                            int nbuck, int E, int N) {
    __shared__ int t[1024];
    int tid = threadIdx.x;
    int v = (tid < nbuck) ? bcounts[tid] : 0;
    t[tid] = v;
    __syncthreads();
    for (int off = 1; off < 1024; off <<= 1) {
        int x = (tid >= off) ? t[tid - off] : 0;
        __syncthreads();
        t[tid] += x;
        __syncthreads();
    }
    if (tid < nbuck) {
        int o = t[tid] - v;       // exclusive
        boff[tid] = o;
        bcur[tid * 16] = o;       // 64B-padded cursor
    }
    if (tid == 0) { boff[nbuck] = E; rowstart[N] = E; }
}

// ---------------- block-local LDS sort + fully parallel flush ----------------
// pack: src (bits 0..19) | local_dst (bits 20..27)
__global__ void edge_sort_scatter(const int* __restrict__ src, const int* __restrict__ dst,
                                  int E, int nbuck,
                                  int* __restrict__ bcur, int* __restrict__ pairs4) {
    __shared__ int hist[392];
    __shared__ int bstart[393];
    __shared__ int cur[392];
    __shared__ int gbase[392];
    __shared__ int wsum[256];
    __shared__ int packed[CHUNK];   // 16 KB
    __shared__ int gpos[CHUNK];     // 16 KB

    int t = threadIdx.x;
    int chunkBase = blockIdx.x * CHUNK;

    // phase 1: local histogram
    for (int i = t; i < nbuck; i += 256) hist[i] = 0;
    __syncthreads();
#pragma unroll
    for (int k = 0; k < EPT; ++k) {
        int e = chunkBase + t + k * 256;
        if (e < E) atomicAdd(&hist[dst[e] >> BNODE_SHIFT], 1);
    }
    __syncthreads();

    // phase 2: exclusive scan of hist (2 items/thread covers <=512 buckets)
    int a0 = (2 * t < nbuck) ? hist[2 * t] : 0;
    int a1 = (2 * t + 1 < nbuck) ? hist[2 * t + 1] : 0;
    int s2 = a0 + a1;
    wsum[t] = s2;
    __syncthreads();
    for (int off = 1; off < 256; off <<= 1) {
        int x = (t >= off) ? wsum[t - off] : 0;
        __syncthreads();
        wsum[t] += x;
        __syncthreads();
    }
    int base = wsum[t] - s2;        // exclusive
    if (2 * t < nbuck)     bstart[2 * t] = base;
    if (2 * t + 1 < nbuck) bstart[2 * t + 1] = base + a0;
    if (t == 255) bstart[nbuck] = wsum[255];
    __syncthreads();

    // phase 2b: reserve global spans; init local cursors
    for (int b = t; b < nbuck; b += 256) {
        int cnt = bstart[b + 1] - bstart[b];
        gbase[b] = cnt ? (atomicAdd(&bcur[b * 16], cnt) - bstart[b]) : 0;
        cur[b] = bstart[b];
    }
    __syncthreads();

    // phase 3: place edges sorted into LDS; record final global position
    #pragma unroll
    for (int k = 0; k < EPT; ++k) {
        int e = chunkBase + t + k * 256;
        if (e < E) {
            int d = dst[e];
            int b = d >> BNODE_SHIFT;
            int pos = atomicAdd(&cur[b], 1);
            packed[pos] = src[e] | ((d & (BNODES - 1)) << 20);
            gpos[pos] = gbase[b] + pos;   // gbase pre-biased by -bstart[b]
        }
    }
    __syncthreads();

    // phase 4: flat parallel flush (coalesced LDS read; runs are contiguous globally)
    int nloc = bstart[nbuck];
    for (int j = t; j < nloc; j += 256)
        pairs4[gpos[j]] = packed[j];
}

// ---------------- exact CSR within each bucket (LDS atomics) ----------------
__global__ void bucket_build(const int* __restrict__ pairs4, const int* __restrict__ boff,
                             int* __restrict__ col, int* __restrict__ rowstart,
                             float* __restrict__ dinv, int N) {
    __shared__ int hist[BNODES];
    __shared__ int cur[BNODES];
    int b = blockIdx.x;
    int lo = boff[b], hi = boff[b + 1];
    int node0 = b << BNODE_SHIFT;
    int tid = threadIdx.x;
    hist[tid] = 0;
    __syncthreads();
    for (int e = lo + tid; e < hi; e += 256)
        atomicAdd(&hist[(pairs4[e] >> 20) & (BNODES - 1)], 1);
    __syncthreads();
    int v = hist[tid];
    cur[tid] = v;
    __syncthreads();
    for (int off = 1; off < BNODES; off <<= 1) {
        int x = (tid >= off) ? cur[tid - off] : 0;
        __syncthreads();
        cur[tid] += x;
        __syncthreads();
    }
    {
        int ex = cur[tid] - v;    // exclusive
        int node = node0 + tid;
        if (node < N) {
            rowstart[node] = lo + ex;
            dinv[node] = rsqrtf((float)(v + 1));   // +1 self-loop
        }
        cur[tid] = ex;            // local cursor
    }
    __syncthreads();
    for (int e = lo + tid; e < hi; e += 256) {
        int pr = pairs4[e];
        int p = atomicAdd(&cur[(pr >> 20) & (BNODES - 1)], 1);
        col[lo + p] = pr & 0xFFFFF;
    }
}

// ---------------- graph boundaries from sorted batch (no atomics) ----------------
__global__ void graph_bounds(const int* __restrict__ batch, int* __restrict__ nodestart,
                             int N, int G) {
    int i = blockIdx.x * blockDim.x + threadIdx.x;
    if (i >= N) return;
    int b = batch[i];
    int bp = (i == 0) ? -1 : batch[i - 1];
    for (int g = bp + 1; g <= b; ++g) nodestart[g] = i;
    if (i == N - 1) nodestart[G] = N;
}

// ---------------- segmented mean pool (bf16 in): one block per graph ----------------
__global__ void pool_mean(const ushort* __restrict__ h, const int* __restrict__ nodestart,
                          float* __restrict__ pooled, int G) {
    int g = blockIdx.x;
    int lo = nodestart[g], hi = nodestart[g + 1];
    int f = threadIdx.x & 63, w = threadIdx.x >> 6;
    float acc = 0.f;
    for (int n = lo + w; n < hi; n += 4) acc += b2f(h[(size_t)n * H + f]);
    __shared__ float red[4][64];
    red[w][f] = acc;
    __syncthreads();
    if (w == 0) {
        float s = red[0][f] + red[1][f] + red[2][f] + red[3][f];
        float c = (float)(hi - lo);
        pooled[g * H + f] = s / fmaxf(c, 1.f);
    }
}

// ---------------- prep: pad x to 16 bf16/row (32B), pre-scaled by dinv ----------------
__global__ void prep_xb(const float* __restrict__ x, const float* __restrict__ dinv,
                        ushort* __restrict__ xb, int N) {
    int i = blockIdx.x * blockDim.x + threadIdx.x;
    if (i >= N * 16) return;
    int n = i >> 4, k = i & 15;
    xb[i] = (k < 9) ? f2b(x[n * 9 + k] * dinv[n]) : (ushort)0;
}

// ---------------- conv1 fused: agg = dinv_i*(sum xb[src] + xb[i]); h = relu(agg@W1+b1) (bf16)
__global__ void conv1_fused(const ushort* __restrict__ xb, const float* __restrict__ dinv,
                            const int* __restrict__ rowstart,
                            const int* __restrict__ col, const float* __restrict__ W1,
                            const float* __restrict__ b1, ushort* __restrict__ out, int N) {
    int gtid = blockIdx.x * blockDim.x + threadIdx.x;
    int i = RFL(gtid >> 6);
    int lane = threadIdx.x & 63;
    int f16 = lane & 15, grp = lane >> 4;
    if (i >= N) return;
    float di = dinv[i];
    float sv = b2f(xb[(size_t)i * 16 + f16]);   // self (already dinv_i-scaled)
    float acc = 0.f;
    int s = rowstart[i], e = rowstart[i + 1];
    for (int base = s; base < e; base += 64) {
        int cnt = e - base;
        if (cnt > 64) cnt = 64;
        int idx = 0;
        if (lane < cnt) idx = __builtin_nontemporal_load(&col[base + lane]);
        for (int j = 0; j < cnt; j += 8) {
            int j0 = j + grp, j1 = j + 4 + grp;
            int s0 = __shfl(idx, j0);
            int s1 = __shfl(idx, j1 & 63);
            float v0 = (j0 < cnt) ? b2f(xb[(size_t)s0 * 16 + f16]) : 0.f;
            float v1 = (j1 < cnt) ? b2f(xb[(size_t)s1 * 16 + f16]) : 0.f;
            acc += v0 + v1;
        }
    }
    // reduce 4 edge-groups
    acc += __shfl_xor(acc, 16);
    acc += __shfl_xor(acc, 32);
    float aggf = di * (acc + sv);            // lane k (k<9) holds agg[k]

    float o = b1[lane];
#pragma unroll
    for (int k = 0; k < 9; ++k) {
        float ak = __shfl(aggf, k);
        o = fmaf(ak, W1[k * H + lane], o);
    }
    __builtin_nontemporal_store(f2b(fmaxf(o, 0.f)), &out[(size_t)i * H + lane]);
}

// ---------------- linear: N x 64 @ 64 x 64 (32 nodes/block, bf16 in/out, dinv-scaled) ----------------
__global__ void lin_h(const ushort* __restrict__ h, const float* __restrict__ W,
                      const float* __restrict__ dinv, ushort* __restrict__ out, int N) {
    __shared__ float Ws[H * H];     // 16 KB
    __shared__ float hs[32 * H];    // 8 KB
    int tid = threadIdx.x;
    int node0 = blockIdx.x * 32;
    for (int idx = tid; idx < H * H; idx += 256) Ws[idx] = W[idx];
    for (int idx = tid; idx < 32 * H; idx += 256) {
        int n = node0 + (idx >> 6);
        hs[idx] = (n < N) ? b2f(h[(size_t)n * H + (idx & 63)]) : 0.f;
    }
    __syncthreads();
    int nlb = tid >> 6, f = tid & 63;   // nlb in 0..3; nodes nlb, nlb+4, ..., nlb+28
    float a[8];
#pragma unroll
    for (int j = 0; j < 8; ++j) a[j] = 0.f;
#pragma unroll 8
    for (int k = 0; k < H; ++k) {
        float w = Ws[k * H + f];
#pragma unroll
        for (int j = 0; j < 8; ++j)
            a[j] = fmaf(hs[(nlb + 4 * j) * H + k], w, a[j]);
    }
#pragma unroll
    for (int j = 0; j < 8; ++j) {
        int n = node0 + nlb + 4 * j;
        if (n < N)
            __builtin_nontemporal_store(f2b(a[j] * dinv[n]), &out[(size_t)n * H + f]);
    }
}

// ---------------- aggregate (bf16 gather, scalarized indices) ----------------
// hb pre-scaled by dinv[src]; out = relu(bias + dinv_i*(sum hb[src] + hb[i])) (bf16)
__global__ void aggregate_b(const ushort* __restrict__ hb, const float* __restrict__ dinv,
                            const int* __restrict__ rowstart,
                            const int* __restrict__ col, const float* __restrict__ bias,
                            ushort* __restrict__ out, int N) {
    int gtid = blockIdx.x * blockDim.x + threadIdx.x;
    int i = RFL(gtid >> 6);   // node = wave (uniform, SGPR)
    int f = threadIdx.x & 63;
    if (i >= N) return;
    float acc = b2f(hb[(size_t)i * H + f]);  // self-loop term (dinv_i*hw[i])
    int s = rowstart[i], e = rowstart[i + 1];
    int p = s;
    for (; p + 8 <= e; p += 8) {
        int i0 = RFL(__builtin_nontemporal_load(&col[p + 0]));
        int i1 = RFL(__builtin_nontemporal_load(&col[p + 1]));
        int i2 = RFL(__builtin_nontemporal_load(&col[p + 2]));
        int i3 = RFL(__builtin_nontemporal_load(&col[p + 3]));
        int i4 = RFL(__builtin_nontemporal_load(&col[p + 4]));
        int i5 = RFL(__builtin_nontemporal_load(&col[p + 5]));
        int i6 = RFL(__builtin_nontemporal_load(&col[p + 6]));
        int i7 = RFL(__builtin_nontemporal_load(&col[p + 7]));
        float v0 = b2f(hb[(size_t)i0 * H + f]);
        float v1 = b2f(hb[(size_t)i1 * H + f]);
        float v2 = b2f(hb[(size_t)i2 * H + f]);
        float v3 = b2f(hb[(size_t)i3 * H + f]);
        float v4 = b2f(hb[(size_t)i4 * H + f]);
        float v5 = b2f(hb[(size_t)i5 * H + f]);
        float v6 = b2f(hb[(size_t)i6 * H + f]);
        float v7 = b2f(hb[(size_t)i7 * H + f]);
        acc += ((v0 + v1) + (v2 + v3)) + ((v4 + v5) + (v6 + v7));
    }
    for (; p < e; ++p) {
        int s0 = RFL(__builtin_nontemporal_load(&col[p]));
        acc += b2f(hb[(size_t)s0 * H + f]);
    }
    float r = fmaxf(bias[f] + dinv[i] * acc, 0.f);
    __builtin_nontemporal_store(f2b(r), &out[(size_t)i * H + f]);
}

// ---------------- final MLP: one wave per graph, shfl-based ----------------
__global__ void mlp(const float* __restrict__ pooled, const float* __restrict__ u,
                    const float* __restrict__ A1, const float* __restrict__ c1,
                    const float* __restrict__ A2, const float* __restrict__ c2,
                    const float* __restrict__ A3, const float* __restrict__ c3,
                    const float* __restrict__ A4, const float* __restrict__ c4,
                    const float* __restrict__ A5, const float* __restrict__ c5,
                    float* __restrict__ out, int G) {
    int wid = (blockIdx.x * blockDim.x + threadIdx.x) >> 6;  // wave = graph
    int lane = threadIdx.x & 63;
    if (wid >= G) return;
    int g = wid;

    float zreg = pooled[g * H + lane];
    float u0 = u[g * 4 + 0], u1 = u[g * 4 + 1], u2 = u[g * 4 + 2], u3 = u[g * 4 + 3];

    // layer 1: 68 -> 50
    float acc = (lane < 50) ? c1[lane] : 0.f;
#pragma unroll
    for (int k = 0; k < 64; ++k) {
        float zk = __shfl(zreg, k);
        float w = (lane < 50) ? A1[k * 50 + lane] : 0.f;
        acc = fmaf(zk, w, acc);
    }
    {
        float w;
        w = (lane < 50) ? A1[64 * 50 + lane] : 0.f; acc = fmaf(u0, w, acc);
        w = (lane < 50) ? A1[65 * 50 + lane] : 0.f; acc = fmaf(u1, w, acc);
        w = (lane < 50) ? A1[66 * 50 + lane] : 0.f; acc = fmaf(u2, w, acc);
        w = (lane < 50) ? A1[67 * 50 + lane] : 0.f; acc = fmaf(u3, w, acc);
    }
    float z1v = fmaxf(acc, 0.f);

    // layer 2: 50 -> 30
    acc = (lane < 30) ? c2[lane] : 0.f;
#pragma unroll
    for (int k = 0; k < 50; ++k) {
        float zk = __shfl(z1v, k);
        float w = (lane < 30) ? A2[k * 30 + lane] : 0.f;
        acc = fmaf(zk, w, acc);
    }
    float z2v = fmaxf(acc, 0.f);

    // layer 3: 30 -> 20
    acc = (lane < 20) ? c3[lane] : 0.f;
#pragma unroll
    for (int k = 0; k < 30; ++k) {
        float zk = __shfl(z2v, k);
        float w = (lane < 20) ? A3[k * 20 + lane] : 0.f;
        acc = fmaf(zk, w, acc);
    }
    float z3v = fmaxf(acc, 0.f);

    // layer 4: 20 -> 5
    acc = (lane < 5) ? c4[lane] : 0.f;
#pragma unroll
    for (int k = 0; k < 20; ++k) {
        float zk = __shfl(z3v, k);
        float w = (lane < 5) ? A4[k * 5 + lane] : 0.f;
        acc = fmaf(zk, w, acc);
    }
    float z4v = fmaxf(acc, 0.f);

    // layer 5: 5 -> 1
    acc = c5[0];
#pragma unroll
    for (int k = 0; k < 5; ++k) {
        float zk = __shfl(z4v, k);
        acc = fmaf(zk, A5[k], acc);
    }
    if (lane == 0) out[g] = fmaxf(acc, 0.f);
}

extern "C" void kernel_launch(void* const* d_in, const int* in_sizes, int n_in,
                              void* d_out, int out_size, void* d_ws, size_t ws_size,
                              hipStream_t stream) {
    const float* x     = (const float*)d_in[0];
    const int*   edge  = (const int*)d_in[1];
    const int*   batch = (const int*)d_in[2];
    const float* u     = (const float*)d_in[3];
    const float* W1 = (const float*)d_in[4];  const float* b1 = (const float*)d_in[5];
    const float* W2 = (const float*)d_in[6];  const float* b2 = (const float*)d_in[7];
    const float* W3 = (const float*)d_in[8];  const float* b3 = (const float*)d_in[9];
    const float* A1 = (const float*)d_in[10]; const float* c1 = (const float*)d_in[11];
    const float* A2 = (const float*)d_in[12]; const float* c2 = (const float*)d_in[13];
    const float* A3 = (const float*)d_in[14]; const float* c3 = (const float*)d_in[15];
    const float* A4 = (const float*)d_in[16]; const float* c4 = (const float*)d_in[17];
    const float* A5 = (const float*)d_in[18]; const float* c5 = (const float*)d_in[19];

    const int N = in_sizes[2];          // 100000
    const int E = in_sizes[1] / 2;      // 3200000
    const int G = in_sizes[3] / 4;      // 256
    const int* src = edge;
    const int* dst = edge + E;
    const int nbuck = (N + BNODES - 1) >> BNODE_SHIFT;   // 391

    // ---- workspace layout (pairs4 aliases hb: pairs4 dead before lin_h writes hb) ----
    char* ws = (char*)d_ws;
    size_t off = 0;
    auto alloc = [&](size_t bytes) -> void* {
        void* p = ws + off;
        off = (off + bytes + 255) & ~(size_t)255;
        return p;
    };
    ushort* hb       = (ushort*)alloc((size_t)N * H * 2);  // dinv-scaled gather operand; aliases pairs4
    ushort* hc       = (ushort*)alloc((size_t)N * H * 2);  // conv output (post-relu features)
    int*    col      = (int*)alloc((size_t)E * 4);
    ushort* xb       = (ushort*)alloc((size_t)N * 16 * 2);
    int*    rowstart = (int*)alloc((size_t)(N + 1) * 4);
    float*  dinv     = (float*)alloc((size_t)N * 4);
    int*    bcounts  = (int*)alloc((size_t)nbuck * 4);
    int*    boff     = (int*)alloc((size_t)(nbuck + 1) * 4);
    int*    bcur     = (int*)alloc((size_t)nbuck * 64);    // 64B-padded cursors
    int*    nodestart= (int*)alloc((size_t)(G + 1) * 4);
    float*  pooled   = (float*)alloc((size_t)G * H * 4);
    int*    pairs4   = (int*)hb;    // E*4 = 12.8MB == N*H*2

    const int nbN   = (N + 255) / 256;
    const int nbAgg = (N + 3) / 4;       // 4 waves/block, wave per node
    const int nchunks = (E + CHUNK - 1) / CHUNK;   // 782

    // ---- CSR build via block-local LDS sort ----
    zero_i32<<<(nbuck + 255) / 256, 256, 0, stream>>>(bcounts, nbuck);
    bucket_hist<<<256, 256, 0, stream>>>(dst, E, bcounts, nbuck);
    bucket_scan<<<1, 1024, 0, stream>>>(bcounts, boff, bcur, rowstart, nbuck, E, N);
    edge_sort_scatter<<<nchunks, 256, 0, stream>>>(src, dst, E, nbuck, bcur, pairs4);
    bucket_build<<<nbuck, 256, 0, stream>>>(pairs4, boff, col, rowstart, dinv, N);
    graph_bounds<<<nbN, 256, 0, stream>>>(batch, nodestart, N, G);

    // ---- conv1 (fused: aggregate 9-wide raw bf16 x, then W1; bf16 out) ----
    prep_xb<<<(N * 16 + 255) / 256, 256, 0, stream>>>(x, dinv, xb, N);
    conv1_fused<<<nbAgg, 256, 0, stream>>>(xb, dinv, rowstart, col, W1, b1, hc, N);
    // ---- conv2 ----
    lin_h<<<(N + 31) / 32, 256, 0, stream>>>(hc, W2, dinv, hb, N);
    aggregate_b<<<nbAgg, 256, 0, stream>>>(hb, dinv, rowstart, col, b2, hc, N);
    // ---- conv3 ----
    lin_h<<<(N + 31) / 32, 256, 0, stream>>>(hc, W3, dinv, hb, N);
    aggregate_b<<<nbAgg, 256, 0, stream>>>(hb, dinv, rowstart, col, b3, hc, N);

    // ---- mean pool + final MLP ----
    pool_mean<<<G, 256, 0, stream>>>(hc, nodestart, pooled, G);
    mlp<<<(G * 64 + 255) / 256, 256, 0, stream>>>(pooled, u, A1, c1, A2, c2, A3, c3,
                                                  A4, c4, A5, c5, (float*)d_out, G);
}

// Round 13
// 399.120 us; speedup vs baseline: 1.2566x; 1.0584x over previous
//
#include <hip/hip_runtime.h>

#define H 64
#define BNODE_SHIFT 8           // 256 nodes per bucket
#define BNODES 256
#define CHUNK 4096              // edges per sort block (16 per thread)
#define EPT 16

// bf16 helpers
static __device__ __forceinline__ float b2f(ushort b) {
    return __uint_as_float(((unsigned int)b) << 16);
}
static __device__ __forceinline__ float b2f_lo(unsigned int u) {
    return __uint_as_float(u << 16);
}
static __device__ __forceinline__ float b2f_hi(unsigned int u) {
    return __uint_as_float(u & 0xFFFF0000u);
}
static __device__ __forceinline__ ushort f2b(float f) {
    unsigned int u = __float_as_uint(f);
    return (ushort)((u + 0x7FFF + ((u >> 16) & 1)) >> 16);
}
#define RFL(x) __builtin_amdgcn_readfirstlane(x)

// ---------------- zero-fill ----------------
__global__ void zero_i32(int* p, int n) {
    int i = blockIdx.x * blockDim.x + threadIdx.x;
    if (i < n) p[i] = 0;
}

// ---------------- bucket histogram (LDS-local then merge) ----------------
__global__ void bucket_hist(const int* __restrict__ dst, int E,
                            int* __restrict__ bcounts, int nbuck) {
    __shared__ int hist[512];
    for (int i = threadIdx.x; i < nbuck; i += blockDim.x) hist[i] = 0;
    __syncthreads();
    for (int e = blockIdx.x * blockDim.x + threadIdx.x; e < E; e += gridDim.x * blockDim.x)
        atomicAdd(&hist[dst[e] >> BNODE_SHIFT], 1);
    __syncthreads();
    for (int i = threadIdx.x; i < nbuck; i += blockDim.x) {
        int v = hist[i];
        if (v) atomicAdd(&bcounts[i], v);
    }
}

// ---------------- bucket offsets scan (1 block) ----------------
__global__ void bucket_scan(const int* __restrict__ bcounts, int* __restrict__ boff,
                            int* __restrict__ bcur, int* __restrict__ rowstart,
                            int nbuck, int E, int N) {
    __shared__ int t[1024];
    int tid = threadIdx.x;
    int v = (tid < nbuck) ? bcounts[tid] : 0;
    t[tid] = v;
    __syncthreads();
    for (int off = 1; off < 1024; off <<= 1) {
        int x = (tid >= off) ? t[tid - off] : 0;
        __syncthreads();
        t[tid] += x;
        __syncthreads();
    }
    if (tid < nbuck) {
        int o = t[tid] - v;       // exclusive
        boff[tid] = o;
        bcur[tid * 16] = o;       // 64B-padded cursor
    }
    if (tid == 0) { boff[nbuck] = E; rowstart[N] = E; }
}

// ---------------- block-local LDS sort + fully parallel flush ----------------
// pack: src (bits 0..19) | local_dst (bits 20..27)
__global__ void edge_sort_scatter(const int* __restrict__ src, const int* __restrict__ dst,
                                  int E, int nbuck,
                                  int* __restrict__ bcur, int* __restrict__ pairs4) {
    __shared__ int hist[392];
    __shared__ int bstart[393];
    __shared__ int cur[392];
    __shared__ int gbase[392];
    __shared__ int wsum[256];
    __shared__ int packed[CHUNK];   // 16 KB
    __shared__ int gpos[CHUNK];     // 16 KB

    int t = threadIdx.x;
    int chunkBase = blockIdx.x * CHUNK;

    // phase 1: load edges into registers once; local histogram
    int dreg[EPT], sreg[EPT];
    for (int i = t; i < nbuck; i += 256) hist[i] = 0;
    __syncthreads();
#pragma unroll
    for (int k = 0; k < EPT; ++k) {
        int e = chunkBase + t + k * 256;
        dreg[k] = (e < E) ? dst[e] : -1;
        sreg[k] = (e < E) ? src[e] : 0;
    }
#pragma unroll
    for (int k = 0; k < EPT; ++k)
        if (dreg[k] >= 0) atomicAdd(&hist[dreg[k] >> BNODE_SHIFT], 1);
    __syncthreads();

    // phase 2: exclusive scan of hist (2 items/thread covers <=512 buckets)
    int a0 = (2 * t < nbuck) ? hist[2 * t] : 0;
    int a1 = (2 * t + 1 < nbuck) ? hist[2 * t + 1] : 0;
    int s2 = a0 + a1;
    wsum[t] = s2;
    __syncthreads();
    for (int off = 1; off < 256; off <<= 1) {
        int x = (t >= off) ? wsum[t - off] : 0;
        __syncthreads();
        wsum[t] += x;
        __syncthreads();
    }
    int base = wsum[t] - s2;        // exclusive
    if (2 * t < nbuck)     bstart[2 * t] = base;
    if (2 * t + 1 < nbuck) bstart[2 * t + 1] = base + a0;
    if (t == 255) bstart[nbuck] = wsum[255];
    __syncthreads();

    // phase 2b: reserve global spans; init local cursors
    for (int b = t; b < nbuck; b += 256) {
        int cnt = bstart[b + 1] - bstart[b];
        gbase[b] = cnt ? (atomicAdd(&bcur[b * 16], cnt) - bstart[b]) : 0;
        cur[b] = bstart[b];
    }
    __syncthreads();

    // phase 3: place edges sorted into LDS; record final global position
#pragma unroll
    for (int k = 0; k < EPT; ++k) {
        if (dreg[k] >= 0) {
            int d = dreg[k];
            int b = d >> BNODE_SHIFT;
            int pos = atomicAdd(&cur[b], 1);
            packed[pos] = sreg[k] | ((d & (BNODES - 1)) << 20);
            gpos[pos] = gbase[b] + pos;   // gbase pre-biased by -bstart[b]
        }
    }
    __syncthreads();

    // phase 4: flat parallel flush
    int nloc = bstart[nbuck];
    for (int j = t; j < nloc; j += 256)
        pairs4[gpos[j]] = packed[j];
}

// ---------------- exact CSR within each bucket (LDS atomics) ----------------
__global__ void bucket_build(const int* __restrict__ pairs4, const int* __restrict__ boff,
                             int* __restrict__ col, int* __restrict__ rowstart,
                             float* __restrict__ dinv, int N) {
    __shared__ int hist[BNODES];
    __shared__ int cur[BNODES];
    int b = blockIdx.x;
    int lo = boff[b], hi = boff[b + 1];
    int node0 = b << BNODE_SHIFT;
    int tid = threadIdx.x;
    hist[tid] = 0;
    __syncthreads();
    for (int e = lo + tid; e < hi; e += 256)
        atomicAdd(&hist[(pairs4[e] >> 20) & (BNODES - 1)], 1);
    __syncthreads();
    int v = hist[tid];
    cur[tid] = v;
    __syncthreads();
    for (int off = 1; off < BNODES; off <<= 1) {
        int x = (tid >= off) ? cur[tid - off] : 0;
        __syncthreads();
        cur[tid] += x;
        __syncthreads();
    }
    {
        int ex = cur[tid] - v;    // exclusive
        int node = node0 + tid;
        if (node < N) {
            rowstart[node] = lo + ex;
            dinv[node] = rsqrtf((float)(v + 1));   // +1 self-loop
        }
        cur[tid] = ex;            // local cursor
    }
    __syncthreads();
    for (int e = lo + tid; e < hi; e += 256) {
        int pr = pairs4[e];
        int p = atomicAdd(&cur[(pr >> 20) & (BNODES - 1)], 1);
        col[lo + p] = pr & 0xFFFFF;
    }
}

// ---------------- graph boundaries from sorted batch (no atomics) ----------------
__global__ void graph_bounds(const int* __restrict__ batch, int* __restrict__ nodestart,
                             int N, int G) {
    int i = blockIdx.x * blockDim.x + threadIdx.x;
    if (i >= N) return;
    int b = batch[i];
    int bp = (i == 0) ? -1 : batch[i - 1];
    for (int g = bp + 1; g <= b; ++g) nodestart[g] = i;
    if (i == N - 1) nodestart[G] = N;
}

// ---------------- segmented mean pool (bf16 in): one block per graph ----------------
__global__ void pool_mean(const ushort* __restrict__ h, const int* __restrict__ nodestart,
                          float* __restrict__ pooled, int G) {
    int g = blockIdx.x;
    int lo = nodestart[g], hi = nodestart[g + 1];
    int f = threadIdx.x & 63, w = threadIdx.x >> 6;
    float acc = 0.f;
    for (int n = lo + w; n < hi; n += 4) acc += b2f(h[(size_t)n * H + f]);
    __shared__ float red[4][64];
    red[w][f] = acc;
    __syncthreads();
    if (w == 0) {
        float s = red[0][f] + red[1][f] + red[2][f] + red[3][f];
        float c = (float)(hi - lo);
        pooled[g * H + f] = s / fmaxf(c, 1.f);
    }
}

// ---------------- prep: pad x to 16 bf16/row (32B), pre-scaled by dinv ----------------
__global__ void prep_xb(const float* __restrict__ x, const float* __restrict__ dinv,
                        ushort* __restrict__ xb, int N) {
    int i = blockIdx.x * blockDim.x + threadIdx.x;
    if (i >= N * 16) return;
    int n = i >> 4, k = i & 15;
    xb[i] = (k < 9) ? f2b(x[n * 9 + k] * dinv[n]) : (ushort)0;
}

// ---------------- conv1 fused: agg = dinv_i*(sum xb[src] + xb[i]); h = relu(agg@W1+b1) (bf16)
__global__ void conv1_fused(const ushort* __restrict__ xb, const float* __restrict__ dinv,
                            const int* __restrict__ rowstart,
                            const int* __restrict__ col, const float* __restrict__ W1,
                            const float* __restrict__ b1, ushort* __restrict__ out, int N) {
    int gtid = blockIdx.x * blockDim.x + threadIdx.x;
    int i = RFL(gtid >> 6);
    int lane = threadIdx.x & 63;
    int f16 = lane & 15, grp = lane >> 4;
    if (i >= N) return;
    float di = dinv[i];
    float sv = b2f(xb[(size_t)i * 16 + f16]);   // self (already dinv_i-scaled)
    float acc = 0.f;
    int s = rowstart[i], e = rowstart[i + 1];
    for (int base = s; base < e; base += 64) {
        int cnt = e - base;
        if (cnt > 64) cnt = 64;
        int idx = 0;
        if (lane < cnt) idx = col[base + lane];
        for (int j = 0; j < cnt; j += 8) {
            int j0 = j + grp, j1 = j + 4 + grp;
            int s0 = __shfl(idx, j0);
            int s1 = __shfl(idx, j1 & 63);
            float v0 = (j0 < cnt) ? b2f(xb[(size_t)s0 * 16 + f16]) : 0.f;
            float v1 = (j1 < cnt) ? b2f(xb[(size_t)s1 * 16 + f16]) : 0.f;
            acc += v0 + v1;
        }
    }
    acc += __shfl_xor(acc, 16);
    acc += __shfl_xor(acc, 32);
    float aggf = di * (acc + sv);            // lane k (k<9) holds agg[k]

    float o = b1[lane];
#pragma unroll
    for (int k = 0; k < 9; ++k) {
        float ak = __shfl(aggf, k);
        o = fmaf(ak, W1[k * H + lane], o);
    }
    out[(size_t)i * H + lane] = f2b(fmaxf(o, 0.f));
}

// ---------------- linear: N x 64 @ 64 x 64 (32 nodes/block, bf16 in/out, dinv-scaled) ----------------
__global__ void lin_h(const ushort* __restrict__ h, const float* __restrict__ W,
                      const float* __restrict__ dinv, ushort* __restrict__ out, int N) {
    __shared__ float Ws[H * H];     // 16 KB
    __shared__ float hs[32 * H];    // 8 KB
    int tid = threadIdx.x;
    int node0 = blockIdx.x * 32;
    for (int idx = tid; idx < H * H; idx += 256) Ws[idx] = W[idx];
    for (int idx = tid; idx < 32 * H; idx += 256) {
        int n = node0 + (idx >> 6);
        hs[idx] = (n < N) ? b2f(h[(size_t)n * H + (idx & 63)]) : 0.f;
    }
    __syncthreads();
    int nlb = tid >> 6, f = tid & 63;   // nodes nlb, nlb+4, ..., nlb+28
    float a[8];
#pragma unroll
    for (int j = 0; j < 8; ++j) a[j] = 0.f;
#pragma unroll 8
    for (int k = 0; k < H; ++k) {
        float w = Ws[k * H + f];
#pragma unroll
        for (int j = 0; j < 8; ++j)
            a[j] = fmaf(hs[(nlb + 4 * j) * H + k], w, a[j]);
    }
#pragma unroll
    for (int j = 0; j < 8; ++j) {
        int n = node0 + nlb + 4 * j;
        if (n < N) out[(size_t)n * H + f] = f2b(a[j] * dinv[n]);
    }
}

// ---------------- aggregate: 4 edges per gather instruction ----------------
// lane: sub = lane&15 (8B chunk = 4 bf16 feats), grp = lane>>4 (edge in quad).
// hb pre-scaled by dinv[src]; out = relu(bias + dinv_i*(sum hb[src] + hb[i])) (bf16)
__global__ void aggregate_q(const ushort* __restrict__ hb, const float* __restrict__ dinv,
                            const int* __restrict__ rowstart,
                            const int* __restrict__ col, const float* __restrict__ bias,
                            ushort* __restrict__ out, int N) {
    int gtid = blockIdx.x * blockDim.x + threadIdx.x;
    int i = RFL(gtid >> 6);   // node = wave (uniform, SGPR)
    int lane = threadIdx.x & 63;
    int sub = lane & 15, grp = lane >> 4;
    if (i >= N) return;
    const uint2* h2 = (const uint2*)hb;           // row i = h2[i*16 + sub]
    bool b4 = (lane & 16) != 0;
    bool b5 = (lane & 32) != 0;
    float a0 = 0.f, a1 = 0.f, a2 = 0.f, a3 = 0.f;
    int s = rowstart[i], e = rowstart[i + 1];
    int p = s;
    for (; p + 4 <= e; p += 4) {
        int i0 = RFL(col[p + 0]);
        int i1 = RFL(col[p + 1]);
        int i2 = RFL(col[p + 2]);
        int i3 = RFL(col[p + 3]);
        int t0 = b4 ? i1 : i0;
        int t1 = b4 ? i3 : i2;
        int sidx = b5 ? t1 : t0;
        uint2 v = h2[(size_t)sidx * 16 + sub];
        a0 += b2f_lo(v.x);
        a1 += b2f_hi(v.x);
        a2 += b2f_lo(v.y);
        a3 += b2f_hi(v.y);
    }
    int r = e - p;                                 // 0..3 tail edges
    if (r) {
        int i0 = RFL(col[p]);
        int i1 = (r > 1) ? RFL(col[p + 1]) : i0;
        int i2 = (r > 2) ? RFL(col[p + 2]) : i0;
        int t0 = b4 ? i1 : i0;
        int t1 = b4 ? i0 : i2;                     // grp3 (masked) -> i0 safe
        int sidx = b5 ? t1 : t0;
        uint2 v = h2[(size_t)sidx * 16 + sub];
        float vm = (grp < r) ? 1.f : 0.f;
        a0 = fmaf(b2f_lo(v.x), vm, a0);
        a1 = fmaf(b2f_hi(v.x), vm, a1);
        a2 = fmaf(b2f_lo(v.y), vm, a2);
        a3 = fmaf(b2f_hi(v.y), vm, a3);
    }
    // reduce 4 edge groups
    a0 += __shfl_xor(a0, 16); a0 += __shfl_xor(a0, 32);
    a1 += __shfl_xor(a1, 16); a1 += __shfl_xor(a1, 32);
    a2 += __shfl_xor(a2, 16); a2 += __shfl_xor(a2, 32);
    a3 += __shfl_xor(a3, 16); a3 += __shfl_xor(a3, 32);
    if (grp == 0) {
        uint2 sv = h2[(size_t)i * 16 + sub];       // self term (once)
        float di = dinv[i];
        const float4* bp = (const float4*)bias;
        float4 bb = bp[sub];
        float r0 = fmaxf(bb.x + di * (a0 + b2f_lo(sv.x)), 0.f);
        float r1 = fmaxf(bb.y + di * (a1 + b2f_hi(sv.x)), 0.f);
        float r2 = fmaxf(bb.z + di * (a2 + b2f_lo(sv.y)), 0.f);
        float r3 = fmaxf(bb.w + di * (a3 + b2f_hi(sv.y)), 0.f);
        uint2 o;
        o.x = (unsigned int)f2b(r0) | ((unsigned int)f2b(r1) << 16);
        o.y = (unsigned int)f2b(r2) | ((unsigned int)f2b(r3) << 16);
        ((uint2*)out)[(size_t)i * 16 + sub] = o;
    }
}

// ---------------- final MLP: one wave per graph, shfl-based ----------------
__global__ void mlp(const float* __restrict__ pooled, const float* __restrict__ u,
                    const float* __restrict__ A1, const float* __restrict__ c1,
                    const float* __restrict__ A2, const float* __restrict__ c2,
                    const float* __restrict__ A3, const float* __restrict__ c3,
                    const float* __restrict__ A4, const float* __restrict__ c4,
                    const float* __restrict__ A5, const float* __restrict__ c5,
                    float* __restrict__ out, int G) {
    int wid = (blockIdx.x * blockDim.x + threadIdx.x) >> 6;  // wave = graph
    int lane = threadIdx.x & 63;
    if (wid >= G) return;
    int g = wid;

    float zreg = pooled[g * H + lane];
    float u0 = u[g * 4 + 0], u1 = u[g * 4 + 1], u2 = u[g * 4 + 2], u3 = u[g * 4 + 3];

    // layer 1: 68 -> 50
    float acc = (lane < 50) ? c1[lane] : 0.f;
#pragma unroll
    for (int k = 0; k < 64; ++k) {
        float zk = __shfl(zreg, k);
        float w = (lane < 50) ? A1[k * 50 + lane] : 0.f;
        acc = fmaf(zk, w, acc);
    }
    {
        float w;
        w = (lane < 50) ? A1[64 * 50 + lane] : 0.f; acc = fmaf(u0, w, acc);
        w = (lane < 50) ? A1[65 * 50 + lane] : 0.f; acc = fmaf(u1, w, acc);
        w = (lane < 50) ? A1[66 * 50 + lane] : 0.f; acc = fmaf(u2, w, acc);
        w = (lane < 50) ? A1[67 * 50 + lane] : 0.f; acc = fmaf(u3, w, acc);
    }
    float z1v = fmaxf(acc, 0.f);

    // layer 2: 50 -> 30
    acc = (lane < 30) ? c2[lane] : 0.f;
#pragma unroll
    for (int k = 0; k < 50; ++k) {
        float zk = __shfl(z1v, k);
        float w = (lane < 30) ? A2[k * 30 + lane] : 0.f;
        acc = fmaf(zk, w, acc);
    }
    float z2v = fmaxf(acc, 0.f);

    // layer 3: 30 -> 20
    acc = (lane < 20) ? c3[lane] : 0.f;
#pragma unroll
    for (int k = 0; k < 30; ++k) {
        float zk = __shfl(z2v, k);
        float w = (lane < 20) ? A3[k * 20 + lane] : 0.f;
        acc = fmaf(zk, w, acc);
    }
    float z3v = fmaxf(acc, 0.f);

    // layer 4: 20 -> 5
    acc = (lane < 5) ? c4[lane] : 0.f;
#pragma unroll
    for (int k = 0; k < 20; ++k) {
        float zk = __shfl(z3v, k);
        float w = (lane < 5) ? A4[k * 5 + lane] : 0.f;
        acc = fmaf(zk, w, acc);
    }
    float z4v = fmaxf(acc, 0.f);

    // layer 5: 5 -> 1
    acc = c5[0];
#pragma unroll
    for (int k = 0; k < 5; ++k) {
        float zk = __shfl(z4v, k);
        acc = fmaf(zk, A5[k], acc);
    }
    if (lane == 0) out[g] = fmaxf(acc, 0.f);
}

extern "C" void kernel_launch(void* const* d_in, const int* in_sizes, int n_in,
                              void* d_out, int out_size, void* d_ws, size_t ws_size,
                              hipStream_t stream) {
    const float* x     = (const float*)d_in[0];
    const int*   edge  = (const int*)d_in[1];
    const int*   batch = (const int*)d_in[2];
    const float* u     = (const float*)d_in[3];
    const float* W1 = (const float*)d_in[4];  const float* b1 = (const float*)d_in[5];
    const float* W2 = (const float*)d_in[6];  const float* b2 = (const float*)d_in[7];
    const float* W3 = (const float*)d_in[8];  const float* b3 = (const float*)d_in[9];
    const float* A1 = (const float*)d_in[10]; const float* c1 = (const float*)d_in[11];
    const float* A2 = (const float*)d_in[12]; const float* c2 = (const float*)d_in[13];
    const float* A3 = (const float*)d_in[14]; const float* c3 = (const float*)d_in[15];
    const float* A4 = (const float*)d_in[16]; const float* c4 = (const float*)d_in[17];
    const float* A5 = (const float*)d_in[18]; const float* c5 = (const float*)d_in[19];

    const int N = in_sizes[2];          // 100000
    const int E = in_sizes[1] / 2;      // 3200000
    const int G = in_sizes[3] / 4;      // 256
    const int* src = edge;
    const int* dst = edge + E;
    const int nbuck = (N + BNODES - 1) >> BNODE_SHIFT;   // 391

    // ---- workspace layout (pairs4 aliases hb: pairs4 dead before lin_h writes hb) ----
    char* ws = (char*)d_ws;
    size_t off = 0;
    auto alloc = [&](size_t bytes) -> void* {
        void* p = ws + off;
        off = (off + bytes + 255) & ~(size_t)255;
        return p;
    };
    ushort* hb       = (ushort*)alloc((size_t)N * H * 2);  // dinv-scaled gather operand; aliases pairs4
    ushort* hc       = (ushort*)alloc((size_t)N * H * 2);  // conv output (post-relu features)
    int*    col      = (int*)alloc((size_t)E * 4);
    ushort* xb       = (ushort*)alloc((size_t)N * 16 * 2);
    int*    rowstart = (int*)alloc((size_t)(N + 1) * 4);
    float*  dinv     = (float*)alloc((size_t)N * 4);
    int*    bcounts  = (int*)alloc((size_t)nbuck * 4);
    int*    boff     = (int*)alloc((size_t)(nbuck + 1) * 4);
    int*    bcur     = (int*)alloc((size_t)nbuck * 64);    // 64B-padded cursors
    int*    nodestart= (int*)alloc((size_t)(G + 1) * 4);
    float*  pooled   = (float*)alloc((size_t)G * H * 4);
    int*    pairs4   = (int*)hb;    // E*4 = 12.8MB == N*H*2

    const int nbN   = (N + 255) / 256;
    const int nbAgg = (N + 3) / 4;       // 4 waves/block, wave per node
    const int nchunks = (E + CHUNK - 1) / CHUNK;   // 782

    // ---- CSR build via block-local LDS sort ----
    zero_i32<<<(nbuck + 255) / 256, 256, 0, stream>>>(bcounts, nbuck);
    bucket_hist<<<256, 256, 0, stream>>>(dst, E, bcounts, nbuck);
    bucket_scan<<<1, 1024, 0, stream>>>(bcounts, boff, bcur, rowstart, nbuck, E, N);
    edge_sort_scatter<<<nchunks, 256, 0, stream>>>(src, dst, E, nbuck, bcur, pairs4);
    bucket_build<<<nbuck, 256, 0, stream>>>(pairs4, boff, col, rowstart, dinv, N);
    graph_bounds<<<nbN, 256, 0, stream>>>(batch, nodestart, N, G);

    // ---- conv1 (fused: aggregate 9-wide raw bf16 x, then W1; bf16 out) ----
    prep_xb<<<(N * 16 + 255) / 256, 256, 0, stream>>>(x, dinv, xb, N);
    conv1_fused<<<nbAgg, 256, 0, stream>>>(xb, dinv, rowstart, col, W1, b1, hc, N);
    // ---- conv2 ----
    lin_h<<<(N + 31) / 32, 256, 0, stream>>>(hc, W2, dinv, hb, N);
    aggregate_q<<<nbAgg, 256, 0, stream>>>(hb, dinv, rowstart, col, b2, hc, N);
    // ---- conv3 ----
    lin_h<<<(N + 31) / 32, 256, 0, stream>>>(hc, W3, dinv, hb, N);
    aggregate_q<<<nbAgg, 256, 0, stream>>>(hb, dinv, rowstart, col, b3, hc, N);

    // ---- mean pool + final MLP ----
    pool_mean<<<G, 256, 0, stream>>>(hc, nodestart, pooled, G);
    mlp<<<(G * 64 + 255) / 256, 256, 0, stream>>>(pooled, u, A1, c1, A2, c2, A3, c3,
                                                  A4, c4, A5, c5, (float*)d_out, G);
}

// Round 14
// 351.063 us; speedup vs baseline: 1.4286x; 1.1369x over previous
//
#include <hip/hip_runtime.h>

#define H 64
#define BNODE_SHIFT 8           // 256 nodes per bucket
#define BNODES 256
#define CHUNK 4096              // edges per sort block (16 per thread)
#define EPT 16

// bf16 helpers
static __device__ __forceinline__ float b2f(ushort b) {
    return __uint_as_float(((unsigned int)b) << 16);
}
static __device__ __forceinline__ ushort f2b(float f) {
    unsigned int u = __float_as_uint(f);
    return (ushort)((u + 0x7FFF + ((u >> 16) & 1)) >> 16);
}
#define RFL(x) __builtin_amdgcn_readfirstlane(x)

// ---------------- fp8 e4m3 helpers (HW conversion if available) ----------------
#if __has_builtin(__builtin_amdgcn_cvt_f32_fp8) && __has_builtin(__builtin_amdgcn_cvt_pk_fp8_f32)
#define HWFP8 1
#else
#define HWFP8 0
#endif

static __device__ __forceinline__ float fp8d(unsigned int b) {
#if HWFP8
    return __builtin_amdgcn_cvt_f32_fp8((int)b, 0);
#else
    unsigned em = b & 0x7F;
    float mag = (em >= 8) ? __uint_as_float((em << 20) + 0x3C000000u)
                          : (float)em * 0.001953125f;          // subnormal: m * 2^-9
    return (b & 0x80) ? -mag : mag;
#endif
}
static __device__ __forceinline__ unsigned char fp8e(float f) {
#if HWFP8
    return (unsigned char)(__builtin_amdgcn_cvt_pk_fp8_f32(f, f, 0, false) & 0xFF);
#else
    unsigned u = __float_as_uint(f);
    unsigned s = (u >> 24) & 0x80;
    float af = fabsf(f);
    if (af >= 448.f) return (unsigned char)(s | 0x7E);
    if (af < 0.0009765625f) return (unsigned char)s;
    if (af < 0.015625f) {
        int m = (int)rintf(af * 512.f);
        if (m > 7) return (unsigned char)(s | 0x08);
        return (unsigned char)(s | m);
    }
    int e; float fr = frexpf(af, &e);
    int q = (int)rintf(fr * 16.f);
    if (q == 16) { q = 8; e += 1; }
    int E = e + 6;
    if (E > 15 || (E == 15 && (q & 7) > 6)) return (unsigned char)(s | 0x7E);
    return (unsigned char)(s | (E << 3) | (q & 7));
#endif
}

// ---------------- zero-fill ----------------
__global__ void zero_i32(int* p, int n) {
    int i = blockIdx.x * blockDim.x + threadIdx.x;
    if (i < n) p[i] = 0;
}

// ---------------- bucket histogram (LDS-local then merge) ----------------
__global__ void bucket_hist(const int* __restrict__ dst, int E,
                            int* __restrict__ bcounts, int nbuck) {
    __shared__ int hist[512];
    for (int i = threadIdx.x; i < nbuck; i += blockDim.x) hist[i] = 0;
    __syncthreads();
    for (int e = blockIdx.x * blockDim.x + threadIdx.x; e < E; e += gridDim.x * blockDim.x)
        atomicAdd(&hist[dst[e] >> BNODE_SHIFT], 1);
    __syncthreads();
    for (int i = threadIdx.x; i < nbuck; i += blockDim.x) {
        int v = hist[i];
        if (v) atomicAdd(&bcounts[i], v);
    }
}

// ---------------- bucket offsets scan (1 block) ----------------
__global__ void bucket_scan(const int* __restrict__ bcounts, int* __restrict__ boff,
                            int* __restrict__ bcur, int* __restrict__ rowstart,
                            int nbuck, int E, int N) {
    __shared__ int t[1024];
    int tid = threadIdx.x;
    int v = (tid < nbuck) ? bcounts[tid] : 0;
    t[tid] = v;
    __syncthreads();
    for (int off = 1; off < 1024; off <<= 1) {
        int x = (tid >= off) ? t[tid - off] : 0;
        __syncthreads();
        t[tid] += x;
        __syncthreads();
    }
    if (tid < nbuck) {
        int o = t[tid] - v;       // exclusive
        boff[tid] = o;
        bcur[tid * 16] = o;       // 64B-padded cursor
    }
    if (tid == 0) { boff[nbuck] = E; rowstart[N] = E; }
}

// ---------------- block-local LDS sort + fully parallel flush ----------------
// pack: src (bits 0..19) | local_dst (bits 20..27)
__global__ void edge_sort_scatter(const int* __restrict__ src, const int* __restrict__ dst,
                                  int E, int nbuck,
                                  int* __restrict__ bcur, int* __restrict__ pairs4) {
    __shared__ int hist[392];
    __shared__ int bstart[393];
    __shared__ int cur[392];
    __shared__ int gbase[392];
    __shared__ int wsum[256];
    __shared__ int packed[CHUNK];   // 16 KB
    __shared__ int gpos[CHUNK];     // 16 KB

    int t = threadIdx.x;
    int chunkBase = blockIdx.x * CHUNK;

    // phase 1: load edges into registers once; local histogram
    int dreg[EPT], sreg[EPT];
    for (int i = t; i < nbuck; i += 256) hist[i] = 0;
    __syncthreads();
#pragma unroll
    for (int k = 0; k < EPT; ++k) {
        int e = chunkBase + t + k * 256;
        dreg[k] = (e < E) ? dst[e] : -1;
        sreg[k] = (e < E) ? src[e] : 0;
    }
#pragma unroll
    for (int k = 0; k < EPT; ++k)
        if (dreg[k] >= 0) atomicAdd(&hist[dreg[k] >> BNODE_SHIFT], 1);
    __syncthreads();

    // phase 2: exclusive scan of hist
    int a0 = (2 * t < nbuck) ? hist[2 * t] : 0;
    int a1 = (2 * t + 1 < nbuck) ? hist[2 * t + 1] : 0;
    int s2 = a0 + a1;
    wsum[t] = s2;
    __syncthreads();
    for (int off = 1; off < 256; off <<= 1) {
        int x = (t >= off) ? wsum[t - off] : 0;
        __syncthreads();
        wsum[t] += x;
        __syncthreads();
    }
    int base = wsum[t] - s2;        // exclusive
    if (2 * t < nbuck)     bstart[2 * t] = base;
    if (2 * t + 1 < nbuck) bstart[2 * t + 1] = base + a0;
    if (t == 255) bstart[nbuck] = wsum[255];
    __syncthreads();

    // phase 2b: reserve global spans; init local cursors
    for (int b = t; b < nbuck; b += 256) {
        int cnt = bstart[b + 1] - bstart[b];
        gbase[b] = cnt ? (atomicAdd(&bcur[b * 16], cnt) - bstart[b]) : 0;
        cur[b] = bstart[b];
    }
    __syncthreads();

    // phase 3: place edges sorted into LDS; record final global position
#pragma unroll
    for (int k = 0; k < EPT; ++k) {
        if (dreg[k] >= 0) {
            int d = dreg[k];
            int b = d >> BNODE_SHIFT;
            int pos = atomicAdd(&cur[b], 1);
            packed[pos] = sreg[k] | ((d & (BNODES - 1)) << 20);
            gpos[pos] = gbase[b] + pos;   // gbase pre-biased by -bstart[b]
        }
    }
    __syncthreads();

    // phase 4: flat parallel flush
    int nloc = bstart[nbuck];
    for (int j = t; j < nloc; j += 256)
        pairs4[gpos[j]] = packed[j];
}

// ---------------- exact CSR within each bucket (LDS atomics) ----------------
__global__ void bucket_build(const int* __restrict__ pairs4, const int* __restrict__ boff,
                             int* __restrict__ col, int* __restrict__ rowstart,
                             float* __restrict__ dinv, int N) {
    __shared__ int hist[BNODES];
    __shared__ int cur[BNODES];
    int b = blockIdx.x;
    int lo = boff[b], hi = boff[b + 1];
    int node0 = b << BNODE_SHIFT;
    int tid = threadIdx.x;
    hist[tid] = 0;
    __syncthreads();
    for (int e = lo + tid; e < hi; e += 256)
        atomicAdd(&hist[(pairs4[e] >> 20) & (BNODES - 1)], 1);
    __syncthreads();
    int v = hist[tid];
    cur[tid] = v;
    __syncthreads();
    for (int off = 1; off < BNODES; off <<= 1) {
        int x = (tid >= off) ? cur[tid - off] : 0;
        __syncthreads();
        cur[tid] += x;
        __syncthreads();
    }
    {
        int ex = cur[tid] - v;    // exclusive
        int node = node0 + tid;
        if (node < N) {
            rowstart[node] = lo + ex;
            dinv[node] = rsqrtf((float)(v + 1));   // +1 self-loop
        }
        cur[tid] = ex;            // local cursor
    }
    __syncthreads();
    for (int e = lo + tid; e < hi; e += 256) {
        int pr = pairs4[e];
        int p = atomicAdd(&cur[(pr >> 20) & (BNODES - 1)], 1);
        col[lo + p] = pr & 0xFFFFF;
    }
}

// ---------------- graph boundaries from sorted batch (no atomics) ----------------
__global__ void graph_bounds(const int* __restrict__ batch, int* __restrict__ nodestart,
                             int N, int G) {
    int i = blockIdx.x * blockDim.x + threadIdx.x;
    if (i >= N) return;
    int b = batch[i];
    int bp = (i == 0) ? -1 : batch[i - 1];
    for (int g = bp + 1; g <= b; ++g) nodestart[g] = i;
    if (i == N - 1) nodestart[G] = N;
}

// ---------------- segmented mean pool (bf16 in): one block per graph ----------------
__global__ void pool_mean(const ushort* __restrict__ h, const int* __restrict__ nodestart,
                          float* __restrict__ pooled, int G) {
    int g = blockIdx.x;
    int lo = nodestart[g], hi = nodestart[g + 1];
    int f = threadIdx.x & 63, w = threadIdx.x >> 6;
    float acc = 0.f;
    for (int n = lo + w; n < hi; n += 4) acc += b2f(h[(size_t)n * H + f]);
    __shared__ float red[4][64];
    red[w][f] = acc;
    __syncthreads();
    if (w == 0) {
        float s = red[0][f] + red[1][f] + red[2][f] + red[3][f];
        float c = (float)(hi - lo);
        pooled[g * H + f] = s / fmaxf(c, 1.f);
    }
}

// ---------------- prep: pad x to 16 fp8/row (16B), pre-scaled by dinv ----------------
__global__ void prep_x8(const float* __restrict__ x, const float* __restrict__ dinv,
                        unsigned char* __restrict__ xb, int N) {
    int i = blockIdx.x * blockDim.x + threadIdx.x;
    if (i >= N * 16) return;
    int n = i >> 4, k = i & 15;
    xb[i] = (k < 9) ? fp8e(x[n * 9 + k] * dinv[n]) : (unsigned char)0;
}

// ---------------- conv1 fused: agg = dinv_i*(sum xb[src] + xb[i]); h = relu(agg@W1+b1) (bf16)
__global__ void conv1_fused(const unsigned char* __restrict__ xb, const float* __restrict__ dinv,
                            const int* __restrict__ rowstart,
                            const int* __restrict__ col, const float* __restrict__ W1,
                            const float* __restrict__ b1, ushort* __restrict__ out, int N) {
    int gtid = blockIdx.x * blockDim.x + threadIdx.x;
    int i = RFL(gtid >> 6);
    int lane = threadIdx.x & 63;
    int f16 = lane & 15, grp = lane >> 4;
    if (i >= N) return;
    float di = dinv[i];
    float sv = fp8d(xb[(size_t)i * 16 + f16]);   // self (already dinv_i-scaled)
    float acc = 0.f;
    int s = rowstart[i], e = rowstart[i + 1];
    for (int base = s; base < e; base += 64) {
        int cnt = e - base;
        if (cnt > 64) cnt = 64;
        int idx = 0;
        if (lane < cnt) idx = col[base + lane];
        for (int j = 0; j < cnt; j += 8) {
            int j0 = j + grp, j1 = j + 4 + grp;
            int s0 = __shfl(idx, j0);
            int s1 = __shfl(idx, j1 & 63);
            float v0 = (j0 < cnt) ? fp8d(xb[(size_t)s0 * 16 + f16]) : 0.f;
            float v1 = (j1 < cnt) ? fp8d(xb[(size_t)s1 * 16 + f16]) : 0.f;
            acc += v0 + v1;
        }
    }
    acc += __shfl_xor(acc, 16);
    acc += __shfl_xor(acc, 32);
    float aggf = di * (acc + sv);            // lane k (k<9) holds agg[k]

    float o = b1[lane];
#pragma unroll
    for (int k = 0; k < 9; ++k) {
        float ak = __shfl(aggf, k);
        o = fmaf(ak, W1[k * H + lane], o);
    }
    out[(size_t)i * H + lane] = f2b(fmaxf(o, 0.f));
}

// ---------------- linear: N x 64 @ 64 x 64 (32 nodes/block, bf16 in, fp8 out, dinv-scaled) ----------------
__global__ void lin_h(const ushort* __restrict__ h, const float* __restrict__ W,
                      const float* __restrict__ dinv, unsigned char* __restrict__ out, int N) {
    __shared__ float Ws[H * H];     // 16 KB
    __shared__ float hs[32 * H];    // 8 KB
    int tid = threadIdx.x;
    int node0 = blockIdx.x * 32;
    for (int idx = tid; idx < H * H; idx += 256) Ws[idx] = W[idx];
    for (int idx = tid; idx < 32 * H; idx += 256) {
        int n = node0 + (idx >> 6);
        hs[idx] = (n < N) ? b2f(h[(size_t)n * H + (idx & 63)]) : 0.f;
    }
    __syncthreads();
    int nlb = tid >> 6, f = tid & 63;   // nodes nlb, nlb+4, ..., nlb+28
    float a[8];
#pragma unroll
    for (int j = 0; j < 8; ++j) a[j] = 0.f;
#pragma unroll 8
    for (int k = 0; k < H; ++k) {
        float w = Ws[k * H + f];
#pragma unroll
        for (int j = 0; j < 8; ++j)
            a[j] = fmaf(hs[(nlb + 4 * j) * H + k], w, a[j]);
    }
#pragma unroll
    for (int j = 0; j < 8; ++j) {
        int n = node0 + nlb + 4 * j;
        if (n < N) out[(size_t)n * H + f] = fp8e(a[j] * dinv[n]);
    }
}

// ---------------- aggregate (fp8 gather, scalarized indices, 16-deep) ----------------
// hb pre-scaled by dinv[src]; out = relu(bias + dinv_i*(sum hb[src] + hb[i])) (bf16)
__global__ void aggregate_8(const unsigned char* __restrict__ hb, const float* __restrict__ dinv,
                            const int* __restrict__ rowstart,
                            const int* __restrict__ col, const float* __restrict__ bias,
                            ushort* __restrict__ out, int N) {
    int gtid = blockIdx.x * blockDim.x + threadIdx.x;
    int i = RFL(gtid >> 6);   // node = wave (uniform, SGPR)
    int f = threadIdx.x & 63;
    if (i >= N) return;
    float acc = fp8d(hb[(size_t)i * H + f]);  // self-loop term (dinv_i*hw[i])
    int s = rowstart[i], e = rowstart[i + 1];
    int p = s;
    for (; p + 16 <= e; p += 16) {
        int idx[16];
#pragma unroll
        for (int k = 0; k < 16; ++k) idx[k] = RFL(col[p + k]);
        float v[16];
#pragma unroll
        for (int k = 0; k < 16; ++k) v[k] = fp8d(hb[(size_t)idx[k] * H + f]);
        float s0 = ((v[0] + v[1]) + (v[2] + v[3])) + ((v[4] + v[5]) + (v[6] + v[7]));
        float s1 = ((v[8] + v[9]) + (v[10] + v[11])) + ((v[12] + v[13]) + (v[14] + v[15]));
        acc += s0 + s1;
    }
    for (; p + 4 <= e; p += 4) {
        int i0 = RFL(col[p + 0]);
        int i1 = RFL(col[p + 1]);
        int i2 = RFL(col[p + 2]);
        int i3 = RFL(col[p + 3]);
        float v0 = fp8d(hb[(size_t)i0 * H + f]);
        float v1 = fp8d(hb[(size_t)i1 * H + f]);
        float v2 = fp8d(hb[(size_t)i2 * H + f]);
        float v3 = fp8d(hb[(size_t)i3 * H + f]);
        acc += (v0 + v1) + (v2 + v3);
    }
    for (; p < e; ++p) {
        int s0 = RFL(col[p]);
        acc += fp8d(hb[(size_t)s0 * H + f]);
    }
    float r = fmaxf(bias[f] + dinv[i] * acc, 0.f);
    out[(size_t)i * H + f] = f2b(r);
}

// ---------------- final MLP: one wave per graph, shfl-based ----------------
__global__ void mlp(const float* __restrict__ pooled, const float* __restrict__ u,
                    const float* __restrict__ A1, const float* __restrict__ c1,
                    const float* __restrict__ A2, const float* __restrict__ c2,
                    const float* __restrict__ A3, const float* __restrict__ c3,
                    const float* __restrict__ A4, const float* __restrict__ c4,
                    const float* __restrict__ A5, const float* __restrict__ c5,
                    float* __restrict__ out, int G) {
    int wid = (blockIdx.x * blockDim.x + threadIdx.x) >> 6;  // wave = graph
    int lane = threadIdx.x & 63;
    if (wid >= G) return;
    int g = wid;

    float zreg = pooled[g * H + lane];
    float u0 = u[g * 4 + 0], u1 = u[g * 4 + 1], u2 = u[g * 4 + 2], u3 = u[g * 4 + 3];

    // layer 1: 68 -> 50
    float acc = (lane < 50) ? c1[lane] : 0.f;
#pragma unroll
    for (int k = 0; k < 64; ++k) {
        float zk = __shfl(zreg, k);
        float w = (lane < 50) ? A1[k * 50 + lane] : 0.f;
        acc = fmaf(zk, w, acc);
    }
    {
        float w;
        w = (lane < 50) ? A1[64 * 50 + lane] : 0.f; acc = fmaf(u0, w, acc);
        w = (lane < 50) ? A1[65 * 50 + lane] : 0.f; acc = fmaf(u1, w, acc);
        w = (lane < 50) ? A1[66 * 50 + lane] : 0.f; acc = fmaf(u2, w, acc);
        w = (lane < 50) ? A1[67 * 50 + lane] : 0.f; acc = fmaf(u3, w, acc);
    }
    float z1v = fmaxf(acc, 0.f);

    // layer 2: 50 -> 30
    acc = (lane < 30) ? c2[lane] : 0.f;
#pragma unroll
    for (int k = 0; k < 50; ++k) {
        float zk = __shfl(z1v, k);
        float w = (lane < 30) ? A2[k * 30 + lane] : 0.f;
        acc = fmaf(zk, w, acc);
    }
    float z2v = fmaxf(acc, 0.f);

    // layer 3: 30 -> 20
    acc = (lane < 20) ? c3[lane] : 0.f;
#pragma unroll
    for (int k = 0; k < 30; ++k) {
        float zk = __shfl(z2v, k);
        float w = (lane < 20) ? A3[k * 20 + lane] : 0.f;
        acc = fmaf(zk, w, acc);
    }
    float z3v = fmaxf(acc, 0.f);

    // layer 4: 20 -> 5
    acc = (lane < 5) ? c4[lane] : 0.f;
#pragma unroll
    for (int k = 0; k < 20; ++k) {
        float zk = __shfl(z3v, k);
        float w = (lane < 5) ? A4[k * 5 + lane] : 0.f;
        acc = fmaf(zk, w, acc);
    }
    float z4v = fmaxf(acc, 0.f);

    // layer 5: 5 -> 1
    acc = c5[0];
#pragma unroll
    for (int k = 0; k < 5; ++k) {
        float zk = __shfl(z4v, k);
        acc = fmaf(zk, A5[k], acc);
    }
    if (lane == 0) out[g] = fmaxf(acc, 0.f);
}

extern "C" void kernel_launch(void* const* d_in, const int* in_sizes, int n_in,
                              void* d_out, int out_size, void* d_ws, size_t ws_size,
                              hipStream_t stream) {
    const float* x     = (const float*)d_in[0];
    const int*   edge  = (const int*)d_in[1];
    const int*   batch = (const int*)d_in[2];
    const float* u     = (const float*)d_in[3];
    const float* W1 = (const float*)d_in[4];  const float* b1 = (const float*)d_in[5];
    const float* W2 = (const float*)d_in[6];  const float* b2 = (const float*)d_in[7];
    const float* W3 = (const float*)d_in[8];  const float* b3 = (const float*)d_in[9];
    const float* A1 = (const float*)d_in[10]; const float* c1 = (const float*)d_in[11];
    const float* A2 = (const float*)d_in[12]; const float* c2 = (const float*)d_in[13];
    const float* A3 = (const float*)d_in[14]; const float* c3 = (const float*)d_in[15];
    const float* A4 = (const float*)d_in[16]; const float* c4 = (const float*)d_in[17];
    const float* A5 = (const float*)d_in[18]; const float* c5 = (const float*)d_in[19];

    const int N = in_sizes[2];          // 100000
    const int E = in_sizes[1] / 2;      // 3200000
    const int G = in_sizes[3] / 4;      // 256
    const int* src = edge;
    const int* dst = edge + E;
    const int nbuck = (N + BNODES - 1) >> BNODE_SHIFT;   // 391

    // ---- workspace layout (pairs4 aliases hc: pairs4 dead before conv1 writes hc) ----
    char* ws = (char*)d_ws;
    size_t off = 0;
    auto alloc = [&](size_t bytes) -> void* {
        void* p = ws + off;
        off = (off + bytes + 255) & ~(size_t)255;
        return p;
    };
    ushort*        hc  = (ushort*)alloc((size_t)N * H * 2);        // bf16 conv output; aliases pairs4 (E*4 <= N*H*2)
    unsigned char* hb  = (unsigned char*)alloc((size_t)N * H);     // fp8 dinv-scaled gather operand (6.4MB)
    int*    col      = (int*)alloc((size_t)E * 4);
    unsigned char* xb = (unsigned char*)alloc((size_t)N * 16);     // fp8 padded input (1.6MB, L2-resident)
    int*    rowstart = (int*)alloc((size_t)(N + 1) * 4);
    float*  dinv     = (float*)alloc((size_t)N * 4);
    int*    bcounts  = (int*)alloc((size_t)nbuck * 4);
    int*    boff     = (int*)alloc((size_t)(nbuck + 1) * 4);
    int*    bcur     = (int*)alloc((size_t)nbuck * 64);    // 64B-padded cursors
    int*    nodestart= (int*)alloc((size_t)(G + 1) * 4);
    float*  pooled   = (float*)alloc((size_t)G * H * 4);
    int*    pairs4   = (int*)hc;    // E*4 = 12.8MB == N*H*2

    const int nbN   = (N + 255) / 256;
    const int nbAgg = (N + 3) / 4;       // 4 waves/block, wave per node
    const int nchunks = (E + CHUNK - 1) / CHUNK;   // 782

    // ---- CSR build via block-local LDS sort ----
    zero_i32<<<(nbuck + 255) / 256, 256, 0, stream>>>(bcounts, nbuck);
    bucket_hist<<<256, 256, 0, stream>>>(dst, E, bcounts, nbuck);
    bucket_scan<<<1, 1024, 0, stream>>>(bcounts, boff, bcur, rowstart, nbuck, E, N);
    edge_sort_scatter<<<nchunks, 256, 0, stream>>>(src, dst, E, nbuck, bcur, pairs4);
    bucket_build<<<nbuck, 256, 0, stream>>>(pairs4, boff, col, rowstart, dinv, N);
    graph_bounds<<<nbN, 256, 0, stream>>>(batch, nodestart, N, G);

    // ---- conv1 (fused: aggregate 9-wide raw fp8 x, then W1; bf16 out) ----
    prep_x8<<<(N * 16 + 255) / 256, 256, 0, stream>>>(x, dinv, xb, N);
    conv1_fused<<<nbAgg, 256, 0, stream>>>(xb, dinv, rowstart, col, W1, b1, hc, N);
    // ---- conv2 ----
    lin_h<<<(N + 31) / 32, 256, 0, stream>>>(hc, W2, dinv, hb, N);
    aggregate_8<<<nbAgg, 256, 0, stream>>>(hb, dinv, rowstart, col, b2, hc, N);
    // ---- conv3 ----
    lin_h<<<(N + 31) / 32, 256, 0, stream>>>(hc, W3, dinv, hb, N);
    aggregate_8<<<nbAgg, 256, 0, stream>>>(hb, dinv, rowstart, col, b3, hc, N);

    // ---- mean pool + final MLP ----
    pool_mean<<<G, 256, 0, stream>>>(hc, nodestart, pooled, G);
    mlp<<<(G * 64 + 255) / 256, 256, 0, stream>>>(pooled, u, A1, c1, A2, c2, A3, c3,
                                                  A4, c4, A5, c5, (float*)d_out, G);
}